// Round 13
// baseline (2782.251 us; speedup 1.0000x reference)
//
#include <hip/hip_runtime.h>
#include <math.h>

#define NPTS 256
#define NB 8

#if __has_builtin(__builtin_amdgcn_sqrtf)
#define FSQRT __builtin_amdgcn_sqrtf
#else
#define FSQRT sqrtf
#endif

#define REP8(M) M(0) M(1) M(2) M(3) M(4) M(5) M(6) M(7)

// Exact fp64 distance (contract off) for the final loss value.
__device__ __forceinline__ double dist3d(double ax, double ay, double az,
                                         double bx, double by, double bz) {
#pragma clang fp contract(off)
  double d0 = ax - bx, d1 = ay - by, d2 = az - bz;
  double s = d0 * d0;
  s = s + d1 * d1;
  s = s + d2 * d2;
  return sqrt(s);
}

__device__ __forceinline__ float distf(float ax, float ay, float az,
                                       float bx, float by, float bz) {
  float d0 = ax - bx, d1 = ay - by, d2 = az - bz;
  return FSQRT(d0 * d0 + d1 * d1 + d2 * d2);
}

// Per-32-lane-group u32 min: 4x row_shr (within-16) + row_bcast:15 leaves
// each group's min in lanes 31/63; one ds_bpermute from lane (grp|31)
// broadcasts it back to the whole group. Both groups served by ONE sequence.
__device__ __forceinline__ unsigned grp_min_bcast(unsigned x, int bad31) {
  unsigned r = x;
  r = min(r, (unsigned)__builtin_amdgcn_update_dpp((int)r, (int)r, 0x111, 0xF, 0xF, false));
  r = min(r, (unsigned)__builtin_amdgcn_update_dpp((int)r, (int)r, 0x112, 0xF, 0xF, false));
  r = min(r, (unsigned)__builtin_amdgcn_update_dpp((int)r, (int)r, 0x114, 0xF, 0xF, false));
  r = min(r, (unsigned)__builtin_amdgcn_update_dpp((int)r, (int)r, 0x118, 0xF, 0xF, false));
  r = min(r, (unsigned)__builtin_amdgcn_update_dpp((int)r, (int)r, 0x142, 0xF, 0xF, false));
  return (unsigned)__builtin_amdgcn_ds_bpermute(bad31, (int)r);
}

__device__ __forceinline__ float bperm_f(int ba, float v) {
  return __int_as_float(__builtin_amdgcn_ds_bpermute(ba, __float_as_int(v)));
}

// Select element cs (0..7, group-uniform) from 8 named scalars P0..P7.
#define SEL8(T, res, P, cs) { \
  T a01 = ((cs) & 1) ? P##1 : P##0; T a23 = ((cs) & 1) ? P##3 : P##2; \
  T a45 = ((cs) & 1) ? P##5 : P##4; T a67 = ((cs) & 1) ? P##7 : P##6; \
  T a03 = ((cs) & 2) ? a23 : a01;   T a47 = ((cs) & 2) ? a67 : a45; \
  res = ((cs) & 4) ? a47 : a03; }

// One block = one wave = TWO samples: lanes 0-31 solve sample 2b, lanes
// 32-63 solve 2b+1, in lockstep. Per-sample algorithm is bit-identical to
// the round-8 best (column reduction + greedy + one reduction-transfer
// sweep, then shortest augmenting path with packed-key group argmin and
// lowest-index tie-break) => same permutations, exact optimum. The shared
// per-pop overhead (argmin butterfly, broadcasts, loop control) is paid
// once per wave for both samples.
__global__ __launch_bounds__(64) void emd_lsa_kernel(
    const float* __restrict__ pred, const float* __restrict__ label,
    double* __restrict__ partial) {
  __shared__ float4 rowd[2 * NPTS];   // {x,y,z,u} per sample slice
  __shared__ float4 colj[2 * NPTS];   // {y0,y1,y2,v}
  __shared__ float short_l[2 * NPTS]; // shortest[] for scanned cols
  __shared__ int path_l[2 * NPTS];    // path[] for scanned cols
  __shared__ int c4r_l[2 * NPTS];     // col4row
  __shared__ int r4c_l[2 * NPTS];     // row4col
  __shared__ int sr_l[2 * NPTS];      // scanned-row flags
  __shared__ int bcfr[2 * NPTS];      // greedy claims
  __shared__ int fq[2 * NPTS];        // free-row queues

  const int lane = threadIdx.x;
  const int gid = lane >> 5;          // group (sample within block)
  const int gl = lane & 31;           // lane within group
  const int gofs = gid << 8;          // LDS slice offset
  const int b = blockIdx.x;
  const int smp = 2 * b + gid;
  const float* xg = pred + (size_t)smp * NPTS * 3;
  const float* yg = label + (size_t)smp * NPTS * 3;
  const int bad31 = ((lane & 32) | 31) << 2;  // bpermute addr of group lane31
  const int rb = gl << 3;             // first owned row/col id (8 per lane)

#define DECL(c) float q##c##x, q##c##y, q##c##z; float vv##c; int rc##c;
  REP8(DECL)
#undef DECL

#define INITC(c) { int j = rb + c; int g = gofs + j; \
    rowd[g] = make_float4(xg[j*3+0], xg[j*3+1], xg[j*3+2], 0.0f); \
    float t0 = yg[j*3+0], t1 = yg[j*3+1], t2 = yg[j*3+2]; \
    colj[g] = make_float4(t0, t1, t2, 0.0f); \
    q##c##x = t0; q##c##y = t1; q##c##z = t2; \
    c4r_l[g] = -1; r4c_l[g] = -1; bcfr[g] = 0x7FFFFFFF; }
  REP8(INITC)
#undef INITC
  __syncthreads();

  // ---- Column reduction: v[j] = min_i cost[i][j], argmin row. ----
#define DECLM(c) float mm##c = 3.4e38f; int im##c = -1;
  REP8(DECLM)
#undef DECLM
  for (int i = 0; i < NPTS; ++i) {
    float4 rd = rowd[gofs + i];  // per-group broadcast (2 addrs/wave: free)
#define CRED(c) { float d = distf(rd.x, rd.y, rd.z, q##c##x, q##c##y, q##c##z); \
    bool u_ = d < mm##c; mm##c = u_ ? d : mm##c; im##c = u_ ? i : im##c; }
    REP8(CRED)
#undef CRED
  }
#define WRV(c) colj[gofs + rb + c].w = mm##c; atomicMin(&bcfr[gofs + im##c], rb + c);
  REP8(WRV)
#undef WRV
  __syncthreads();
#define GRD(c) if (bcfr[gofs + im##c] == rb + c) { r4c_l[gofs + rb + c] = im##c; c4r_l[gofs + im##c] = rb + c; }
  REP8(GRD)
#undef GRD
  __syncthreads();

  // ---- Reduction transfer (parallel Jacobi, round-8): for assigned rows,
  // mu_i = min_{j != phi(i)} (c_ij - v_j); v[phi(i)] -= mu_i; u_i = mu_i.
  {
#define LDR(c) float4 rD##c = rowd[gofs + rb + c]; int ja##c = c4r_l[gofs + rb + c]; float mu##c = 3.4e38f;
    REP8(LDR)
#undef LDR
    for (int j = 0; j < NPTS; ++j) {
      float4 cj = colj[gofs + j];
#define RT(c) { float d = distf(rD##c.x, rD##c.y, rD##c.z, cj.x, cj.y, cj.z) - cj.w; \
      d = (j == ja##c) ? 3.4e38f : d; mu##c = fminf(mu##c, d); }
      REP8(RT)
#undef RT
    }
#define WRT(c) if (ja##c >= 0) { colj[gofs + ja##c].w -= mu##c; rowd[gofs + rb + c].w = mu##c; }
    REP8(WRT)
#undef WRT
  }
  __syncthreads();
#define LDV(c) vv##c = colj[gofs + rb + c].w; rc##c = r4c_l[gofs + rb + c];
  REP8(LDV)
#undef LDV

  // ---- Build per-group free-row queue (deterministic ballot compaction).
  int nf;
  {
#define FLG(c) int fl##c = (c4r_l[gofs + rb + c] < 0) ? 1 : 0; \
    unsigned long long bb##c = __ballot(fl##c); \
    unsigned gm##c = (unsigned)(bb##c >> (gid * 32));
    REP8(FLG)
#undef FLG
    unsigned lt = (1u << gl) - 1u;
    int off = __popc(gm0 & lt) + __popc(gm1 & lt) + __popc(gm2 & lt) + __popc(gm3 & lt)
            + __popc(gm4 & lt) + __popc(gm5 & lt) + __popc(gm6 & lt) + __popc(gm7 & lt);
#define PUT(c) if (fl##c) { fq[gofs + off] = rb + c; off++; }
    REP8(PUT)
#undef PUT
    nf = __popc(gm0) + __popc(gm1) + __popc(gm2) + __popc(gm3)
       + __popc(gm4) + __popc(gm5) + __popc(gm6) + __popc(gm7);
  }
  __syncthreads();
  int onf = __shfl(nf, lane ^ 32);
  int nfmax = max(nf, onf);  // uniform across the wave

  const float INF = 3.4e38f;

  // ---- Shortest augmenting path; both groups advance in lockstep. ----
  for (int t = 0; t < nfmax; ++t) {
    bool act = (t < nf);  // group-uniform
    if (act) {
      int cur_row = fq[gofs + t];
#define SINI(c) float sh##c = INF; int pp##c = -1;
      REP8(SINI)
#undef SINI
      int scm = 0;  // scanned-col bitmask for owned cols
      *(int4*)&sr_l[gofs + rb] = make_int4(0, 0, 0, 0);
      *(int4*)&sr_l[gofs + rb + 4] = make_int4(0, 0, 0, 0);
      float4 r0 = rowd[gofs + cur_row];
      float xi = r0.x, yi = r0.y, zi = r0.z, ui = r0.w;
      float min_val = 0.0f;
      int i = cur_row;
      int sink = -1;

      while (true) {
        sr_l[gofs + i] = 1;  // group-uniform addr: write-collapses
        float base_ = min_val - ui;
#define SSTEP(c) unsigned k##c; { float d = distf(xi, yi, zi, q##c##x, q##c##y, q##c##z); \
        float r = (base_ + d) - vv##c; \
        int scb = (scm >> c) & 1; \
        bool u_ = (r < sh##c) && !scb; \
        sh##c = u_ ? r : sh##c; pp##c = u_ ? i : pp##c; \
        unsigned kk = (__float_as_uint(fmaxf(sh##c, 0.0f)) & 0xFFFFFF00u) | (unsigned)(rb + c); \
        k##c = scb ? 0xFFFFFFFFu : kk; }
        REP8(SSTEP)
#undef SSTEP
        unsigned lkey = min(min(min(k0, k1), min(k2, k3)),
                            min(min(k4, k5), min(k6, k7)));
        unsigned best = grp_min_bcast(lkey, bad31);  // per-group min
        int jstar = (int)(best & 0xFFu);             // group-uniform
        int csel = jstar & 7;
        int wlane = (lane & 32) | (jstar >> 3);      // winner lane (in group)

        float els; SEL8(float, els, sh, csel)
        int nls;   SEL8(int, nls, rc, csel)
        int pps;   SEL8(int, pps, pp, csel)
        if (lane == wlane) {  // owner publishes scanned-col state
          short_l[gofs + jstar] = els;
          path_l[gofs + jstar] = pps;
        }
        scm |= ((gl == (jstar >> 3)) ? 1 : 0) << csel;

        int ba = wlane << 2;
        min_val = bperm_f(ba, els);                       // exact value
        int nr = __builtin_amdgcn_ds_bpermute(ba, nls);   // next row
        if (nr < 0) { sink = jstar; break; }
        i = nr;
        float4 ri = rowd[gofs + i];  // group-broadcast read
        xi = ri.x; yi = ri.y; zi = ri.z; ui = ri.w;
      }

      // Dual update (before augmentation, matching the reference).
#define DUALU(c) { int row = rb + c; \
      if (sr_l[gofs + row]) { \
        float du = (row == cur_row) ? min_val : (min_val - short_l[gofs + c4r_l[gofs + row]]); \
        rowd[gofs + row].w += du; } \
      if ((scm >> c) & 1) vv##c -= min_val - sh##c; }
      REP8(DUALU)
#undef DUALU

      if (gl == 0) {  // per-group augment walk (two walks run concurrently)
        int jj = sink;
        while (true) {
          int ii = path_l[gofs + jj];
          r4c_l[gofs + jj] = ii;
          int tmp = c4r_l[gofs + ii];
          c4r_l[gofs + ii] = jj;
          jj = tmp;
          if (ii == cur_row) break;
        }
      }
#define RFR(c) rc##c = r4c_l[gofs + rb + c];
      REP8(RFR)
#undef RFR
    }
  }
  __syncthreads();

  // ---- Final loss: exact fp64 matched distances; per-group reduce. ----
  double s = 0.0;
#define FIN(c) { int row = rb + c; int j = c4r_l[gofs + row]; \
    float4 rd = rowd[gofs + row]; float4 cj = colj[gofs + j]; \
    s += dist3d((double)rd.x, (double)rd.y, (double)rd.z, \
                (double)cj.x, (double)cj.y, (double)cj.z); }
  REP8(FIN)
#undef FIN
  for (int m = 1; m < 32; m <<= 1) s += __shfl_xor(s, m);
  if (gl == 0) partial[smp] = s;
}

__global__ void emd_finalize_kernel(const double* __restrict__ partial,
                                    float* __restrict__ out) {
  if (threadIdx.x == 0 && blockIdx.x == 0) {
    double s = 0.0;
    for (int b = 0; b < NB; ++b) s += partial[b];
    out[0] = (float)(s / (double)(NB * NPTS));
  }
}

extern "C" void kernel_launch(void* const* d_in, const int* in_sizes, int n_in,
                              void* d_out, int out_size, void* d_ws, size_t ws_size,
                              hipStream_t stream) {
  const float* pred = (const float*)d_in[0];
  const float* label = (const float*)d_in[1];
  double* partial = (double*)d_ws;  // 8 doubles
  emd_lsa_kernel<<<4, 64, 0, stream>>>(pred, label, partial);
  emd_finalize_kernel<<<1, 64, 0, stream>>>(partial, (float*)d_out);
}

// Round 14
// 1277.953 us; speedup vs baseline: 2.1771x; 2.1771x over previous
//
#include <hip/hip_runtime.h>
#include <math.h>

#define NPTS 256
#define NB 8

#if __has_builtin(__builtin_amdgcn_sqrtf)
#define FSQRT __builtin_amdgcn_sqrtf
#else
#define FSQRT sqrtf
#endif

// Exact fp64 distance (contract off) for the final loss value.
__device__ __forceinline__ double dist3d(double ax, double ay, double az,
                                         double bx, double by, double bz) {
#pragma clang fp contract(off)
  double d0 = ax - bx;
  double d1 = ay - by;
  double d2 = az - bz;
  double s = d0 * d0;
  s = s + d1 * d1;
  s = s + d2 * d2;
  return sqrt(s);
}

__device__ __forceinline__ float distf(float ax, float ay, float az,
                                       float bx, float by, float bz) {
  float d0 = ax - bx, d1 = ay - by, d2 = az - bz;
  return FSQRT(d0 * d0 + d1 * d1 + d2 * d2);
}

// Wave64 min-reduce of a u32 via DPP (row_shr 1/2/4/8 + row_bcast 15/31),
// broadcast via readlane(63). Pure VALU/SALU — no LDS traffic.
__device__ __forceinline__ unsigned wave_min_u32(unsigned x) {
  unsigned r = x;
  r = min(r, (unsigned)__builtin_amdgcn_update_dpp((int)r, (int)r, 0x111, 0xF, 0xF, false));
  r = min(r, (unsigned)__builtin_amdgcn_update_dpp((int)r, (int)r, 0x112, 0xF, 0xF, false));
  r = min(r, (unsigned)__builtin_amdgcn_update_dpp((int)r, (int)r, 0x114, 0xF, 0xF, false));
  r = min(r, (unsigned)__builtin_amdgcn_update_dpp((int)r, (int)r, 0x118, 0xF, 0xF, false));
  r = min(r, (unsigned)__builtin_amdgcn_update_dpp((int)r, (int)r, 0x142, 0xF, 0xF, false));
  r = min(r, (unsigned)__builtin_amdgcn_update_dpp((int)r, (int)r, 0x143, 0xF, 0xF, false));
  return (unsigned)__builtin_amdgcn_readlane((int)r, 63);
}

// One block = one 64-lane wave per batch sample.
// LAPJV-style init: column reduction + greedy + one REDUCTION TRANSFER
// sweep (v[phi(i)] -= mu_i, u_i = mu_i — parallel Jacobi form, keeps dual
// feasibility + CS => SAP phase still exactly optimal), then the
// zero-LDS-read shortest-augmenting-path loop (payload-carrying tournament,
// winner-lane readlane broadcast). Best-measured variant (1278 us; rounds
// 8 and 11 bit-identical). Structural floor: ~95 serial searches x ~100
// pops x ~295 cy issue+stall chain — VALU-issue-bound on a single wave,
// not a HW roofline (VALUBusy 0.37%).
__global__ __launch_bounds__(64) void emd_lsa_kernel(
    const float* __restrict__ pred, const float* __restrict__ label,
    double* __restrict__ partial) {
  __shared__ float4 rowd[NPTS];   // {x0,x1,x2,u}
  __shared__ float4 colj[NPTS];   // {y0,y1,y2,v}
  __shared__ float short_l[NPTS]; // shortest[] for scanned cols
  __shared__ int path_l[NPTS];    // path[] for scanned cols
  __shared__ int c4r_l[NPTS];     // col4row
  __shared__ int r4c_l[NPTS];     // row4col
  __shared__ int sr_l[NPTS];      // scanned-row flags
  __shared__ int bcfr[NPTS];      // greedy claims
  __shared__ int fq[NPTS];        // free-row queue

  const int lane = threadIdx.x;
  const int b = blockIdx.x;
  const float* xg = pred + (size_t)b * NPTS * 3;
  const float* yg = label + (size_t)b * NPTS * 3;

  const int cid0 = lane * 4, cid1 = cid0 + 1, cid2 = cid0 + 2, cid3 = cid0 + 3;

  float q0x, q0y, q0z, q1x, q1y, q1z, q2x, q2y, q2z, q3x, q3y, q3z;
  float vv0, vv1, vv2, vv3;
  int rc0, rc1, rc2, rc3;

#define INITC(c) { int j = cid##c; \
    rowd[j] = make_float4(xg[j*3+0], xg[j*3+1], xg[j*3+2], 0.0f); \
    float t0 = yg[j*3+0], t1 = yg[j*3+1], t2 = yg[j*3+2]; \
    colj[j] = make_float4(t0, t1, t2, 0.0f); \
    q##c##x = t0; q##c##y = t1; q##c##z = t2; \
    c4r_l[j] = -1; r4c_l[j] = -1; bcfr[j] = 0x7FFFFFFF; }
  INITC(0) INITC(1) INITC(2) INITC(3)
#undef INITC
  __syncthreads();

  // ---- Column reduction: v[j] = min_i cost[i][j], argmin row. ----
  float mm0 = 3.4e38f, mm1 = 3.4e38f, mm2 = 3.4e38f, mm3 = 3.4e38f;
  int im0 = -1, im1 = -1, im2 = -1, im3 = -1;
  for (int i = 0; i < NPTS; ++i) {
    float4 rd = rowd[i];  // broadcast read; independent iterations pipeline
#define CRED(c) { float d = distf(rd.x, rd.y, rd.z, q##c##x, q##c##y, q##c##z); \
    bool u_ = d < mm##c; mm##c = u_ ? d : mm##c; im##c = u_ ? i : im##c; }
    CRED(0) CRED(1) CRED(2) CRED(3)
#undef CRED
  }
  colj[cid0].w = mm0; colj[cid1].w = mm1;
  colj[cid2].w = mm2; colj[cid3].w = mm3;
  atomicMin(&bcfr[im0], cid0);
  atomicMin(&bcfr[im1], cid1);
  atomicMin(&bcfr[im2], cid2);
  atomicMin(&bcfr[im3], cid3);
  __syncthreads();
  if (bcfr[im0] == cid0) { r4c_l[cid0] = im0; c4r_l[im0] = cid0; }
  if (bcfr[im1] == cid1) { r4c_l[cid1] = im1; c4r_l[im1] = cid1; }
  if (bcfr[im2] == cid2) { r4c_l[cid2] = im2; c4r_l[im2] = cid2; }
  if (bcfr[im3] == cid3) { r4c_l[cid3] = im3; c4r_l[im3] = cid3; }
  __syncthreads();

  // ---- Reduction transfer (parallel Jacobi): for assigned rows i,
  // mu_i = min_{j != phi(i)} (c_ij - v_j); v[phi(i)] -= mu_i; u_i = mu_i.
  // v only decreases and assigned edges stay tight => feasibility + CS kept.
  {
    float4 rD0 = rowd[cid0], rD1 = rowd[cid1], rD2 = rowd[cid2], rD3 = rowd[cid3];
    int ja0 = c4r_l[cid0], ja1 = c4r_l[cid1], ja2 = c4r_l[cid2], ja3 = c4r_l[cid3];
    float mu0 = 3.4e38f, mu1 = 3.4e38f, mu2 = 3.4e38f, mu3 = 3.4e38f;
    for (int j = 0; j < NPTS; ++j) {
      float4 cj = colj[j];  // broadcast read
#define RT(c) { float d = distf(rD##c.x, rD##c.y, rD##c.z, cj.x, cj.y, cj.z) - cj.w; \
      d = (j == ja##c) ? 3.4e38f : d; \
      mu##c = fminf(mu##c, d); }
      RT(0) RT(1) RT(2) RT(3)
#undef RT
    }
    // Lockstep wave: all scans done before writes. Each row writes only
    // its own phi's v (matching => distinct cols).
    if (ja0 >= 0) { colj[ja0].w -= mu0; rowd[cid0].w = mu0; }
    if (ja1 >= 0) { colj[ja1].w -= mu1; rowd[cid1].w = mu1; }
    if (ja2 >= 0) { colj[ja2].w -= mu2; rowd[cid2].w = mu2; }
    if (ja3 >= 0) { colj[ja3].w -= mu3; rowd[cid3].w = mu3; }
  }
  __syncthreads();
  vv0 = colj[cid0].w; vv1 = colj[cid1].w;
  vv2 = colj[cid2].w; vv3 = colj[cid3].w;
  rc0 = r4c_l[cid0]; rc1 = r4c_l[cid1]; rc2 = r4c_l[cid2]; rc3 = r4c_l[cid3];

  // ---- Build free-row queue via ballot compaction. ----
  int nf;
  {
    int4 cc = *(int4*)&c4r_l[cid0];
    bool f0 = cc.x < 0, f1 = cc.y < 0, f2 = cc.z < 0, f3 = cc.w < 0;
    unsigned long long b0 = __ballot(f0), b1 = __ballot(f1);
    unsigned long long b2 = __ballot(f2), b3 = __ballot(f3);
    unsigned long long lt = (1ull << lane) - 1ull;
    int off = __popcll(b0 & lt) + __popcll(b1 & lt) + __popcll(b2 & lt) + __popcll(b3 & lt);
    if (f0) fq[off++] = cid0;
    if (f1) fq[off++] = cid1;
    if (f2) fq[off++] = cid2;
    if (f3) fq[off++] = cid3;
    nf = __popcll(b0) + __popcll(b1) + __popcll(b2) + __popcll(b3);
  }
  __syncthreads();

  const float INF = 3.4e38f;

  // ---- Shortest augmenting path for each free row. ----
  for (int t = 0; t < nf; ++t) {
    int cur_row = fq[t];  // uniform broadcast

    float sh0 = INF, sh1 = INF, sh2 = INF, sh3 = INF;
    int pp0 = -1, pp1 = -1, pp2 = -1, pp3 = -1;
    int sc0 = 0, sc1 = 0, sc2 = 0, sc3 = 0;
    *(int4*)&sr_l[cid0] = make_int4(0, 0, 0, 0);

    // Assigned-row records for owned columns: constant during the search.
    float4 cr0 = rowd[rc0 < 0 ? 0 : rc0];
    float4 cr1 = rowd[rc1 < 0 ? 0 : rc1];
    float4 cr2 = rowd[rc2 < 0 ? 0 : rc2];
    float4 cr3 = rowd[rc3 < 0 ? 0 : rc3];

    float xi, yi, zi, ui;
    { float4 r0 = rowd[cur_row]; xi = r0.x; yi = r0.y; zi = r0.z; ui = r0.w; }
    __syncthreads();

    float min_val = 0.0f;
    int i = cur_row;
    int sink = -1;

    while (true) {
      sr_l[i] = 1;  // same addr+value from all lanes (write-collapse)
      float base = min_val - ui;
      unsigned k0, k1, k2, k3;
#define SSTEP(c) { float d = distf(xi, yi, zi, q##c##x, q##c##y, q##c##z); \
      float r = (base + d) - vv##c; \
      bool u_ = (r < sh##c) && (sc##c == 0); \
      sh##c = u_ ? r : sh##c; \
      pp##c = u_ ? i : pp##c; \
      unsigned kk = (__float_as_uint(fmaxf(sh##c, 0.0f)) & 0xFFFFFF00u) | (unsigned)cid##c; \
      k##c = sc##c ? 0xFFFFFFFFu : kk; }
      SSTEP(0) SSTEP(1) SSTEP(2) SSTEP(3)
#undef SSTEP
      // Local 4-way tournament; payload selects run parallel to the key ops.
      bool t01 = k1 < k0;
      unsigned ka = t01 ? k1 : k0;
      float ea = t01 ? sh1 : sh0; int pa = t01 ? pp1 : pp0; int na = t01 ? rc1 : rc0;
      float axa = t01 ? cr1.x : cr0.x, aya = t01 ? cr1.y : cr0.y;
      float aza = t01 ? cr1.z : cr0.z, aua = t01 ? cr1.w : cr0.w;
      bool t23 = k3 < k2;
      unsigned kb = t23 ? k3 : k2;
      float eb = t23 ? sh3 : sh2; int pb = t23 ? pp3 : pp2; int nb2 = t23 ? rc3 : rc2;
      float axb = t23 ? cr3.x : cr2.x, ayb = t23 ? cr3.y : cr2.y;
      float azb = t23 ? cr3.z : cr2.z, aub = t23 ? cr3.w : cr2.w;
      bool tf = kb < ka;
      unsigned lkey = tf ? kb : ka;
      float el = tf ? eb : ea; int pl = tf ? pb : pa; int nl = tf ? nb2 : na;
      float nx = tf ? axb : axa, ny = tf ? ayb : aya;
      float nz = tf ? azb : aza, nu = tf ? aub : aua;

      unsigned best = wave_min_u32(lkey);  // uniform after readlane(63)
      int jstar = (int)(best & 0xFFu);
      int w = jstar >> 2;  // winner lane; its local pick == jstar&3

      if (lane == w) {  // publish scanned-col state (off-chain stores)
        short_l[jstar] = el;
        path_l[jstar] = pl;
      }
      sc0 |= (cid0 == jstar); sc1 |= (cid1 == jstar);
      sc2 |= (cid2 == jstar); sc3 |= (cid3 == jstar);

      min_val = __int_as_float(__builtin_amdgcn_readlane(__float_as_int(el), w));
      int nr = __builtin_amdgcn_readlane(nl, w);
      if (nr < 0) { sink = jstar; break; }
      i = nr;
      xi = __int_as_float(__builtin_amdgcn_readlane(__float_as_int(nx), w));
      yi = __int_as_float(__builtin_amdgcn_readlane(__float_as_int(ny), w));
      zi = __int_as_float(__builtin_amdgcn_readlane(__float_as_int(nz), w));
      ui = __int_as_float(__builtin_amdgcn_readlane(__float_as_int(nu), w));
    }
    __syncthreads();  // publish short_l / path_l / sr_l

    // Dual update (rows via LDS flags, cols via register state).
#define DUALU(c) { int row = cid##c; \
      if (sr_l[row]) { \
        float du = (row == cur_row) ? min_val : (min_val - short_l[c4r_l[row]]); \
        rowd[row].w += du; } \
      if (sc##c) vv##c -= min_val - sh##c; }
    DUALU(0) DUALU(1) DUALU(2) DUALU(3)
#undef DUALU
    __syncthreads();

    if (lane == 0) {  // augment along the alternating path
      int jj = sink;
      while (true) {
        int ii = path_l[jj];
        r4c_l[jj] = ii;
        int tmp = c4r_l[ii];
        c4r_l[ii] = jj;
        jj = tmp;
        if (ii == cur_row) break;
      }
    }
    __syncthreads();
    rc0 = r4c_l[cid0]; rc1 = r4c_l[cid1]; rc2 = r4c_l[cid2]; rc3 = r4c_l[cid3];
    __syncthreads();
  }

  // ---- Final loss: exact fp64 matched distances. ----
  double s = 0.0;
#define FIN(c) { int row = cid##c; int j = c4r_l[row]; float4 rd = rowd[row]; \
    float4 cj = colj[j]; \
    s += dist3d((double)rd.x, (double)rd.y, (double)rd.z, \
                (double)cj.x, (double)cj.y, (double)cj.z); }
  FIN(0) FIN(1) FIN(2) FIN(3)
#undef FIN
  for (int m = 1; m < 64; m <<= 1) s += __shfl_xor(s, m);
  if (lane == 0) partial[b] = s;
}

__global__ void emd_finalize_kernel(const double* __restrict__ partial,
                                    float* __restrict__ out) {
  if (threadIdx.x == 0 && blockIdx.x == 0) {
    double s = 0.0;
    for (int b = 0; b < NB; ++b) s += partial[b];
    out[0] = (float)(s / (double)(NB * NPTS));
  }
}

extern "C" void kernel_launch(void* const* d_in, const int* in_sizes, int n_in,
                              void* d_out, int out_size, void* d_ws, size_t ws_size,
                              hipStream_t stream) {
  const float* pred = (const float*)d_in[0];
  const float* label = (const float*)d_in[1];
  double* partial = (double*)d_ws;  // 8 doubles
  emd_lsa_kernel<<<NB, 64, 0, stream>>>(pred, label, partial);
  emd_finalize_kernel<<<1, 64, 0, stream>>>(partial, (float*)d_out);
}